// Round 6
// baseline (467.068 us; speedup 1.0000x reference)
//
#include <hip/hip_runtime.h>
#include <hip/hip_bf16.h>

#define N_NODE  50000
#define N_PAD   50048   // buffer row count (391*128); staging rows clamped, stores guarded
#define N_GRAPH 1024
#define DD      512
#define BKT     32
#define NKT     16      // 512 / 32

typedef __attribute__((ext_vector_type(8))) short bf16x8;
typedef __attribute__((ext_vector_type(4))) float f32x4;

__device__ __forceinline__ unsigned short f2bf(float f) {
  unsigned int u = __builtin_bit_cast(unsigned int, f);
  return (unsigned short)((u + 0x7FFFu + ((u >> 16) & 1u)) >> 16);  // RTN-even
}

__device__ __forceinline__ float bf2f(unsigned short h) {
  unsigned int u = ((unsigned int)h) << 16;
  return __builtin_bit_cast(float, u);
}

__device__ __forceinline__ void gload16(const void* g, void* l) {
  __builtin_amdgcn_global_load_lds(
      (const __attribute__((address_space(1))) unsigned int*)g,
      (__attribute__((address_space(3))) unsigned int*)l, 16, 0, 0);
}

// T1: bijective XCD-chunk remap (m204 variant)
__device__ __forceinline__ int xcd_remap(int bid, int nwg) {
  int xcd = bid & 7;
  int local = bid >> 3;
  int q = nwg >> 3, r = nwg & 7;
  int base = (xcd < r) ? xcd * (q + 1) : r * (q + 1) + (xcd - r) * q;
  return base + local;
}

// ---- cast kernels -----------------------------------------------------------

__global__ void cast_pad_kernel(const float* __restrict__ src,
                                unsigned short* __restrict__ dst,
                                int srcRows, int dstRows) {
  long long base = ((long long)blockIdx.x * blockDim.x + threadIdx.x) * 8;
  if (base >= (long long)dstRows * DD) return;
  int row = (int)(base >> 9);
  bf16x8 o;
  if (row < srcRows) {
    float4 x0 = reinterpret_cast<const float4*>(src + base)[0];
    float4 x1 = reinterpret_cast<const float4*>(src + base)[1];
    o[0] = (short)f2bf(x0.x); o[1] = (short)f2bf(x0.y);
    o[2] = (short)f2bf(x0.z); o[3] = (short)f2bf(x0.w);
    o[4] = (short)f2bf(x1.x); o[5] = (short)f2bf(x1.y);
    o[6] = (short)f2bf(x1.z); o[7] = (short)f2bf(x1.w);
  } else {
    for (int i = 0; i < 8; ++i) o[i] = 0;
  }
  *reinterpret_cast<bf16x8*>(dst + base) = o;
}

struct WPtrs { const float* p[8]; };

__global__ void cast_w_kernel(WPtrs ps, unsigned short* __restrict__ dst) {
  long long base = ((long long)blockIdx.x * blockDim.x + threadIdx.x) * 8;
  int mat = (int)(base >> 18);
  int off = (int)(base & 262143LL);
  const float* s = ps.p[mat] + off;
  float4 x0 = reinterpret_cast<const float4*>(s)[0];
  float4 x1 = reinterpret_cast<const float4*>(s)[1];
  bf16x8 o;
  o[0] = (short)f2bf(x0.x); o[1] = (short)f2bf(x0.y);
  o[2] = (short)f2bf(x0.z); o[3] = (short)f2bf(x0.w);
  o[4] = (short)f2bf(x1.x); o[5] = (short)f2bf(x1.y);
  o[6] = (short)f2bf(x1.z); o[7] = (short)f2bf(x1.w);
  *reinterpret_cast<bf16x8*>(dst + base) = o;
}

__global__ void zeropad_kernel(unsigned short* __restrict__ H) {
  long long i = (long long)blockIdx.x * blockDim.x + threadIdx.x;
  long long base = (long long)N_NODE * DD + i * 8;
  if (base < (long long)N_PAD * DD) {
    bf16x8 z;
    for (int k = 0; k < 8; ++k) z[k] = 0;
    *reinterpret_cast<bf16x8*>(H + base) = z;
  }
}

// ---- 256x256 GEMM core: BK=32, 4-slot circular LDS, m201-style phases ------
// T2 swizzle as R4 (verified 0 conflicts): LDS [256][4 slots x 16B]; phys slot
// p of row r holds logical slot p ^ ((r>>1)&3); source inverse-swizzled.
// Stage s (one K-step's A+B tiles, 4 gloads/thread: A,A,B,B) -> LDS slot s&3.
// Stage indices run CONTINUOUSLY across a block's tiles: during tile ti's
// steps 13..15 the next tile's stages k=0,1,2 are issued. Steady-state wait
// at each step end: vmcnt(8) retires exactly stage t+1 (12 loads in flight).
// Never vmcnt(0) mid-stream (T4). Each K-step = 2 phases:
//   Ph_a {read a0-3,b0-3 + issue A-pair -> bar -> 16 MFMA (m0-3) -> bar}
//   Ph_b {read a4-7      + issue B-pair -> bar -> 16 MFMA (m4-7) -> wait+bar}

struct Ptrs { const unsigned short *a0, *a1, *b0, *b1; };

__device__ __forceinline__ void issueA(const Ptrs& p, int kelem,
                                       unsigned short* sA, int wid) {
  unsigned short* dA = sA + wid * 512;   // wave-uniform; HW adds lane*16B
  gload16(p.a0 + kelem, dA);
  gload16(p.a1 + kelem, dA + 4096);
}
__device__ __forceinline__ void issueB(const Ptrs& p, int kelem,
                                       unsigned short* sB, int wid) {
  unsigned short* dB = sB + wid * 512;
  gload16(p.b0 + kelem, dB);
  gload16(p.b1 + kelem, dB + 4096);
}

// issue stages 0,1,2 of the FIRST tile, retire stage 0
__device__ __forceinline__ void pipe_prologue(const Ptrs& p,
                                              unsigned short* As,
                                              unsigned short* Bs, int wid) {
  issueA(p, 0, As, wid);              issueB(p, 0, Bs, wid);
  issueA(p, BKT, As + 8192, wid);     issueB(p, BKT, Bs + 8192, wid);
  issueA(p, 2 * BKT, As + 16384, wid); issueB(p, 2 * BKT, Bs + 16384, wid);
  asm volatile("s_waitcnt vmcnt(8)" ::: "memory");
  __builtin_amdgcn_sched_barrier(0);
  __builtin_amdgcn_s_barrier();
}

__device__ __forceinline__ void ktile16(
    int last, const Ptrs& cur, const Ptrs& nxt,
    unsigned short* As, unsigned short* Bs,
    int wid, int rA, int rB, int pa8, int pb8, f32x4 acc[8][4]) {
  #pragma unroll
  for (int t = 0; t < NKT; ++t) {
    const unsigned short* as = As + (t & 3) * 8192;
    const unsigned short* bs = Bs + (t & 3) * 8192;
    unsigned short* wA = As + ((t + 3) & 3) * 8192;
    unsigned short* wB = Bs + ((t + 3) & 3) * 8192;
    // ---- phase A -----------------------------------------------------------
    bf16x8 a[4], b[4];
    #pragma unroll
    for (int m = 0; m < 4; ++m)
      a[m] = *reinterpret_cast<const bf16x8*>(as + (rA + m * 16) * BKT + pa8);
    #pragma unroll
    for (int n = 0; n < 4; ++n)
      b[n] = *reinterpret_cast<const bf16x8*>(bs + (rB + n * 16) * BKT + pb8);
    if (t < NKT - 3)       issueA(cur, (t + 3) * BKT, wA, wid);
    else if (!last)        issueA(nxt, (t - (NKT - 3)) * BKT, wA, wid);
    __builtin_amdgcn_s_barrier();
    __builtin_amdgcn_s_setprio(1);
    #pragma unroll
    for (int m = 0; m < 4; ++m)
      #pragma unroll
      for (int n = 0; n < 4; ++n)
        acc[m][n] = __builtin_amdgcn_mfma_f32_16x16x32_bf16(a[m], b[n], acc[m][n], 0, 0, 0);
    __builtin_amdgcn_s_setprio(0);
    __builtin_amdgcn_s_barrier();
    // ---- phase B -----------------------------------------------------------
    bf16x8 a2[4];
    #pragma unroll
    for (int m = 0; m < 4; ++m)
      a2[m] = *reinterpret_cast<const bf16x8*>(as + (rA + 64 + m * 16) * BKT + pa8);
    if (t < NKT - 3)       issueB(cur, (t + 3) * BKT, wB, wid);
    else if (!last)        issueB(nxt, (t - (NKT - 3)) * BKT, wB, wid);
    __builtin_amdgcn_s_barrier();
    __builtin_amdgcn_s_setprio(1);
    #pragma unroll
    for (int m = 0; m < 4; ++m)
      #pragma unroll
      for (int n = 0; n < 4; ++n)
        acc[4 + m][n] = __builtin_amdgcn_mfma_f32_16x16x32_bf16(a2[m], b[n], acc[4 + m][n], 0, 0, 0);
    __builtin_amdgcn_s_setprio(0);
    // ---- end-of-step wait (counted; tail drains only on the LAST tile) -----
    if (!last || t < NKT - 3) {
      asm volatile("s_waitcnt vmcnt(8)" ::: "memory");
      __builtin_amdgcn_sched_barrier(0);
      __builtin_amdgcn_s_barrier();
    } else if (t == NKT - 3) {
      asm volatile("s_waitcnt vmcnt(4)" ::: "memory");
      __builtin_amdgcn_sched_barrier(0);
      __builtin_amdgcn_s_barrier();
    } else if (t == NKT - 2) {
      asm volatile("s_waitcnt vmcnt(0)" ::: "memory");
      __builtin_amdgcn_sched_barrier(0);
      __builtin_amdgcn_s_barrier();
    }
    // t == NKT-1 && last: nothing
  }
}

// ---- FF GEMM: C = [relu](A@W^T + bias [+ C]); 2-tile persistent l-blocks ---

template <int RELU, int CADD>
__global__ __launch_bounds__(512, 2) void gemm_ff256(
    const unsigned short* __restrict__ Al, const unsigned short* __restrict__ Wl,
    const float* __restrict__ biasl, unsigned short* __restrict__ Cl, int nblkL,
    const unsigned short* __restrict__ Ag, const unsigned short* __restrict__ Wg,
    const float* __restrict__ biasg, unsigned short* __restrict__ Cg) {
  __shared__ unsigned short As[4 * 8192];
  __shared__ unsigned short Bs[4 * 8192];
  const int tid = threadIdx.x;
  const int lane = tid & 63, wid = tid >> 6;
  const int wr = wid >> 2, wc = wid & 3;

  int b = xcd_remap(blockIdx.x, gridDim.x);
  const unsigned short *A, *W;
  const float* bias;
  unsigned short* C;
  long long maxA, maxStore, bcol;
  int r0, rstride, nt;
  if (b < nblkL) {            // l-problem: 196 rows x 2 cols, 2 tiles/block
    A = Al; W = Wl; bias = biasl; C = Cl; maxA = N_PAD - 1; maxStore = N_PAD;
    bcol = (long long)(b & 1) * 256; r0 = b >> 1; rstride = 98; nt = 2;
  } else {                    // g-problem: 4 rows x 2 cols, 1 tile/block
    int gi = b - nblkL;
    A = Ag; W = Wg; bias = biasg; C = Cg; maxA = N_GRAPH - 1; maxStore = N_GRAPH;
    bcol = (long long)(gi & 1) * 256; r0 = gi >> 1; rstride = 0; nt = 1;
  }

  const int srow = tid >> 2;
  const int sslot = (((tid & 3) ^ ((tid >> 3) & 3))) * 8;
  const unsigned short* Bb0 = W + (bcol + srow) * DD + sslot;
  const unsigned short* Bb1 = W + (bcol + 128 + srow) * DD + sslot;

  auto mk = [&](int ti) {
    long long br = (long long)(r0 + rstride * ti) * 256;
    long long x0 = br + srow;        if (x0 > maxA) x0 = maxA;
    long long x1 = br + 128 + srow;  if (x1 > maxA) x1 = maxA;
    Ptrs p; p.a0 = A + x0 * DD + sslot; p.a1 = A + x1 * DD + sslot;
    p.b0 = Bb0; p.b1 = Bb1; return p;
  };

  const int rA = wr * 128 + (lane & 15);
  const int rB = wc * 64 + (lane & 15);
  const int q = lane >> 4;
  const int pa8 = (q ^ ((rA >> 1) & 3)) * 8;
  const int pb8 = (q ^ ((rB >> 1) & 3)) * 8;

  float bv[4];
  #pragma unroll
  for (int n = 0; n < 4; ++n) bv[n] = bias[bcol + wc * 64 + n * 16 + (lane & 15)];

  f32x4 acc[8][4];
  f32x4 zero = {0.f, 0.f, 0.f, 0.f};
  #pragma unroll
  for (int m = 0; m < 8; ++m)
    #pragma unroll
    for (int n = 0; n < 4; ++n) acc[m][n] = zero;

  Ptrs cur = mk(0);
  Ptrs nxt = (nt > 1) ? mk(1) : cur;
  pipe_prologue(cur, As, Bs, wid);

  for (int ti = 0; ti < nt; ++ti) {
    const int lastT = (ti == nt - 1);
    ktile16(lastT, cur, nxt, As, Bs, wid, rA, rB, pa8, pb8, acc);

    const long long brow = (long long)(r0 + rstride * ti) * 256;
    #pragma unroll
    for (int m = 0; m < 8; ++m) {
      #pragma unroll
      for (int j = 0; j < 4; ++j) {
        const long long rowg = brow + wr * 128 + m * 16 + (lane >> 4) * 4 + j;
        if (rowg < maxStore) {
          #pragma unroll
          for (int n = 0; n < 4; ++n) {
            const long long col = bcol + wc * 64 + n * 16 + (lane & 15);
            float v = acc[m][n][j] + bv[n];
            if constexpr (RELU) v = fmaxf(v, 0.f);
            if constexpr (CADD) v += bf2f(C[rowg * DD + col]);
            C[rowg * DD + col] = f2bf(v);
          }
        }
      }
    }
    if (!lastT) {
      #pragma unroll
      for (int m = 0; m < 8; ++m)
        #pragma unroll
        for (int n = 0; n < 4; ++n) acc[m][n] = zero;
      cur = nxt;  // next-next doesn't exist for nt==2
    }
  }
}

// ---- res GEMM + fused JSD; 256 persistent blocks, 3-4 tiles each -----------
// accum[0] = sum_diag (LN2 - softplus(-v))
// accum[1] = sum_all  (softplus(-v) + v)   (rows < N_PAD; zero rows -> ln2)
// accum[2] = sum_diag (softplus(-v) + v)

__global__ __launch_bounds__(512, 2) void gemm_jsd256(
    const unsigned short* __restrict__ A, const unsigned short* __restrict__ B,
    const int* __restrict__ batch, double* __restrict__ accum) {
  __shared__ unsigned short As[4 * 8192];
  __shared__ unsigned short Bs[4 * 8192];
  __shared__ float sred[24];
  const int tid = threadIdx.x;
  const int lane = tid & 63, wid = tid >> 6;
  const int wr = wid >> 2, wc = wid & 3;

  const int bid = blockIdx.x;           // grid == 256 exactly
  const long long bcol = (long long)(bid & 3) * 256;
  const int r0 = bid >> 2;              // 0..63; tiles: rows r0 + 64*k < 196
  const int nt = (r0 < 4) ? 4 : 3;

  const int srow = tid >> 2;
  const int sslot = (((tid & 3) ^ ((tid >> 3) & 3))) * 8;
  const unsigned short* Bb0 = B + (bcol + srow) * DD + sslot;
  const unsigned short* Bb1 = B + (bcol + 128 + srow) * DD + sslot;

  auto mk = [&](int ti) {
    long long br = (long long)(r0 + 64 * ti) * 256;
    long long x0 = br + srow;        if (x0 > N_PAD - 1) x0 = N_PAD - 1;
    long long x1 = br + 128 + srow;  if (x1 > N_PAD - 1) x1 = N_PAD - 1;
    Ptrs p; p.a0 = A + x0 * DD + sslot; p.a1 = A + x1 * DD + sslot;
    p.b0 = Bb0; p.b1 = Bb1; return p;
  };

  const int rA = wr * 128 + (lane & 15);
  const int rB = wc * 64 + (lane & 15);
  const int q = lane >> 4;
  const int pa8 = (q ^ ((rA >> 1) & 3)) * 8;
  const int pb8 = (q ^ ((rB >> 1) & 3)) * 8;

  f32x4 acc[8][4];
  f32x4 zero = {0.f, 0.f, 0.f, 0.f};
  #pragma unroll
  for (int m = 0; m < 8; ++m)
    #pragma unroll
    for (int n = 0; n < 4; ++n) acc[m][n] = zero;

  const float LN2 = 0.69314718055994530942f;
  float sAll = 0.f, sPos = 0.f, sDiag = 0.f;

  Ptrs cur = mk(0);
  Ptrs nxt = (nt > 1) ? mk(1) : cur;
  pipe_prologue(cur, As, Bs, wid);

  for (int ti = 0; ti < nt; ++ti) {
    const int lastT = (ti == nt - 1);
    ktile16(lastT, cur, nxt, As, Bs, wid, rA, rB, pa8, pb8, acc);

    // epilogue: no LDS, no barriers -> overlaps in-flight next-tile stages
    const long long brow = (long long)(r0 + 64 * ti) * 256;
    #pragma unroll
    for (int m = 0; m < 8; ++m) {
      #pragma unroll
      for (int j = 0; j < 4; ++j) {
        const int lr = wr * 128 + m * 16 + (lane >> 4) * 4 + j;
        const long long rowg = brow + lr;
        if (rowg < N_PAD) {
          const int bg = (rowg < N_NODE) ? batch[rowg] : -1;
          #pragma unroll
          for (int n = 0; n < 4; ++n) {
            const int col = (int)bcol + wc * 64 + n * 16 + (lane & 15);
            float v = acc[m][n][j];
            float t = __expf(-fabsf(v));
            float spn = fmaxf(-v, 0.f) + __logf(1.0f + t);   // softplus(-v)
            sAll += spn + v;
            if (col == bg) {
              sPos += LN2 - spn;
              sDiag += spn + v;
            }
          }
        }
      }
    }
    if (!lastT) {
      #pragma unroll
      for (int m = 0; m < 8; ++m)
        #pragma unroll
        for (int n = 0; n < 4; ++n) acc[m][n] = zero;
      cur = nxt;
      nxt = (ti + 2 < nt) ? mk(ti + 2) : nxt;
    }
  }

  #pragma unroll
  for (int off = 32; off > 0; off >>= 1) {
    sAll  += __shfl_down(sAll, off);
    sPos  += __shfl_down(sPos, off);
    sDiag += __shfl_down(sDiag, off);
  }
  if (lane == 0) { sred[wid] = sPos; sred[8 + wid] = sAll; sred[16 + wid] = sDiag; }
  __syncthreads();
  if (tid == 0) {
    float p = 0.f, a = 0.f, d = 0.f;
    #pragma unroll
    for (int w = 0; w < 8; ++w) { p += sred[w]; a += sred[8 + w]; d += sred[16 + w]; }
    atomicAdd(accum,     (double)p);
    atomicAdd(accum + 1, (double)a);
    atomicAdd(accum + 2, (double)d);
  }
}

__global__ void finalize_kernel(const double* __restrict__ accum,
                                float* __restrict__ out) {
  if (threadIdx.x == 0 && blockIdx.x == 0) {
    const double LN2 = 0.6931471805599453094172321;
    double posSum = accum[0];
    double negSum = (accum[1] - accum[2])
                  - ((double)N_PAD * N_GRAPH - (double)N_NODE) * LN2;
    double Epos = posSum / (double)N_NODE;
    double Eneg = negSum / ((double)N_NODE * (double)(N_GRAPH - 1));
    out[0] = (float)(Eneg - Epos);
  }
}

// ---- launch -----------------------------------------------------------------

extern "C" void kernel_launch(void* const* d_in, const int* in_sizes, int n_in,
                              void* d_out, int out_size, void* d_ws, size_t ws_size,
                              hipStream_t stream) {
  const float* node  = (const float*)d_in[0];
  const float* graph = (const float*)d_in[1];
  const int*   batch = (const int*)d_in[2];
  const float* lw0 = (const float*)d_in[3];
  const float* lb0 = (const float*)d_in[4];
  const float* lw1 = (const float*)d_in[5];
  const float* lb1 = (const float*)d_in[6];
  const float* lw2 = (const float*)d_in[7];
  const float* lb2 = (const float*)d_in[8];
  const float* lws = (const float*)d_in[9];
  const float* lbs = (const float*)d_in[10];
  const float* gw0 = (const float*)d_in[11];
  const float* gb0 = (const float*)d_in[12];
  const float* gw1 = (const float*)d_in[13];
  const float* gb1 = (const float*)d_in[14];
  const float* gw2 = (const float*)d_in[15];
  const float* gb2 = (const float*)d_in[16];
  const float* gws = (const float*)d_in[17];
  const float* gbs = (const float*)d_in[18];

  // workspace layout (identical to R2-R4)
  char* ws = (char*)d_ws;
  double*         accum = (double*)ws;                          // 24 B
  unsigned short* WB  = (unsigned short*)(ws + 256);            // 8 x 512x512 bf16
  unsigned short* XB  = (unsigned short*)(ws + 4194560LL);      // [N_PAD,512] bf16
  unsigned short* H1  = (unsigned short*)(ws + 55443712LL);
  unsigned short* H2  = (unsigned short*)(ws + 106692864LL);
  unsigned short* GXB = (unsigned short*)(ws + 157942016LL);
  unsigned short* GH1 = (unsigned short*)(ws + 158990592LL);
  unsigned short* GH2 = (unsigned short*)(ws + 160039168LL);
  if (ws_size < 161087744ULL) return;

  hipMemsetAsync(accum, 0, 32, stream);

  WPtrs wp;
  wp.p[0] = lw0; wp.p[1] = lw1; wp.p[2] = lw2; wp.p[3] = lws;
  wp.p[4] = gw0; wp.p[5] = gw1; wp.p[6] = gw2; wp.p[7] = gws;
  cast_w_kernel<<<1024, 256, 0, stream>>>(wp, WB);
  cast_pad_kernel<<<12512, 256, 0, stream>>>(node, XB, N_NODE, N_PAD);
  cast_pad_kernel<<<256, 256, 0, stream>>>(graph, GXB, N_GRAPH, N_GRAPH);

  dim3 blk(512);
  const int nblkL = 98 * 2;            // l: 98 row-pairs x 2 cols, 2 tiles each
  const int nblkG = 4 * 2;             // g: 4 rows x 2 cols, 1 tile each
  dim3 gff(nblkL + nblkG);             // 204 blocks
  dim3 gr(256);                        // jsd: 64 row-groups x 4 cols, 3-4 tiles

  gemm_ff256<1, 0><<<gff, blk, 0, stream>>>(
      XB, WB + 0 * 262144, lb0, H1, nblkL,
      GXB, WB + 4 * 262144, gb0, GH1);
  gemm_ff256<1, 0><<<gff, blk, 0, stream>>>(
      H1, WB + 1 * 262144, lb1, H2, nblkL,
      GH1, WB + 5 * 262144, gb1, GH2);
  gemm_ff256<1, 0><<<gff, blk, 0, stream>>>(
      H2, WB + 2 * 262144, lb2, H1, nblkL,
      GH2, WB + 6 * 262144, gb2, GH1);
  gemm_ff256<0, 1><<<gff, blk, 0, stream>>>(
      XB, WB + 3 * 262144, lbs, H1, nblkL,
      GXB, WB + 7 * 262144, gbs, GH1);

  zeropad_kernel<<<12, 256, 0, stream>>>(H1);
  gemm_jsd256<<<gr, blk, 0, stream>>>(H1, GH1, batch, accum);
  finalize_kernel<<<1, 64, 0, stream>>>(accum, (float*)d_out);
}

// Round 7
// 421.076 us; speedup vs baseline: 1.1092x; 1.1092x over previous
//
#include <hip/hip_runtime.h>
#include <hip/hip_bf16.h>

#define N_NODE  50000
#define N_PAD   50048   // buffer row count (391*128); staging rows clamped, stores guarded
#define N_GRAPH 1024
#define DD      512
#define BKT     32
#define NKT     16      // 512 / 32

typedef __attribute__((ext_vector_type(8))) short bf16x8;
typedef __attribute__((ext_vector_type(4))) float f32x4;

__device__ __forceinline__ unsigned short f2bf(float f) {
  unsigned int u = __builtin_bit_cast(unsigned int, f);
  return (unsigned short)((u + 0x7FFFu + ((u >> 16) & 1u)) >> 16);  // RTN-even
}

__device__ __forceinline__ float bf2f(unsigned short h) {
  unsigned int u = ((unsigned int)h) << 16;
  return __builtin_bit_cast(float, u);
}

__device__ __forceinline__ void gload16(const void* g, void* l) {
  __builtin_amdgcn_global_load_lds(
      (const __attribute__((address_space(1))) unsigned int*)g,
      (__attribute__((address_space(3))) unsigned int*)l, 16, 0, 0);
}

// T1: bijective XCD-chunk remap (m204 variant)
__device__ __forceinline__ int xcd_remap(int bid, int nwg) {
  int xcd = bid & 7;
  int local = bid >> 3;
  int q = nwg >> 3, r = nwg & 7;
  int base = (xcd < r) ? xcd * (q + 1) : r * (q + 1) + (xcd - r) * q;
  return base + local;
}

// ---- cast kernels -----------------------------------------------------------

__global__ void cast_pad_kernel(const float* __restrict__ src,
                                unsigned short* __restrict__ dst,
                                int srcRows, int dstRows) {
  long long base = ((long long)blockIdx.x * blockDim.x + threadIdx.x) * 8;
  if (base >= (long long)dstRows * DD) return;
  int row = (int)(base >> 9);
  bf16x8 o;
  if (row < srcRows) {
    float4 x0 = reinterpret_cast<const float4*>(src + base)[0];
    float4 x1 = reinterpret_cast<const float4*>(src + base)[1];
    o[0] = (short)f2bf(x0.x); o[1] = (short)f2bf(x0.y);
    o[2] = (short)f2bf(x0.z); o[3] = (short)f2bf(x0.w);
    o[4] = (short)f2bf(x1.x); o[5] = (short)f2bf(x1.y);
    o[6] = (short)f2bf(x1.z); o[7] = (short)f2bf(x1.w);
  } else {
    for (int i = 0; i < 8; ++i) o[i] = 0;
  }
  *reinterpret_cast<bf16x8*>(dst + base) = o;
}

struct WPtrs { const float* p[8]; };

__global__ void cast_w_kernel(WPtrs ps, unsigned short* __restrict__ dst) {
  long long base = ((long long)blockIdx.x * blockDim.x + threadIdx.x) * 8;
  int mat = (int)(base >> 18);
  int off = (int)(base & 262143LL);
  const float* s = ps.p[mat] + off;
  float4 x0 = reinterpret_cast<const float4*>(s)[0];
  float4 x1 = reinterpret_cast<const float4*>(s)[1];
  bf16x8 o;
  o[0] = (short)f2bf(x0.x); o[1] = (short)f2bf(x0.y);
  o[2] = (short)f2bf(x0.z); o[3] = (short)f2bf(x0.w);
  o[4] = (short)f2bf(x1.x); o[5] = (short)f2bf(x1.y);
  o[6] = (short)f2bf(x1.z); o[7] = (short)f2bf(x1.w);
  *reinterpret_cast<bf16x8*>(dst + base) = o;
}

__global__ void zeropad_kernel(unsigned short* __restrict__ H) {
  long long i = (long long)blockIdx.x * blockDim.x + threadIdx.x;
  long long base = (long long)N_NODE * DD + i * 8;
  if (base < (long long)N_PAD * DD) {
    bf16x8 z;
    for (int k = 0; k < 8; ++k) z[k] = 0;
    *reinterpret_cast<bf16x8*>(H + base) = z;
  }
}

// ---- 256x256 GEMM core: BK=32, 4-slot circular LDS, counted vmcnt ----------
// BYTE-IDENTICAL to R4's proven core (116 VGPR, 0 bank conflicts, no spill).
// T2 swizzle: LDS [256][4 slots x 16B]; phys slot p of row r holds logical
// slot p ^ ((r>>1)&3); staging source inverse-swizzled (rule 21).
// Pipeline: stages t,t+1,t+2 outstanding at iter t's wait -> vmcnt(8) retires
// stage t. Never vmcnt(0) until the tail (T4). Fully drained on return.

struct StageSrc { const unsigned short *a0, *a1, *b0, *b1; };

__device__ __forceinline__ void issue_stage(const StageSrc& s, int kelem,
                                            unsigned short* sA, unsigned short* sB,
                                            int wid) {
  unsigned short* dA = sA + wid * 512;   // wave-uniform; HW adds lane*16B
  unsigned short* dB = sB + wid * 512;
  gload16(s.a0 + kelem, dA);
  gload16(s.a1 + kelem, dA + 4096);
  gload16(s.b0 + kelem, dB);
  gload16(s.b1 + kelem, dB + 4096);
}

__device__ __forceinline__ void gemm_core256(
    const StageSrc& s, unsigned short* As, unsigned short* Bs,
    int wid, int rA, int rB, int pa8, int pb8, f32x4 acc[8][4]) {
  issue_stage(s, 0, As, Bs, wid);
  issue_stage(s, BKT, As + 8192, Bs + 8192, wid);
  issue_stage(s, 2 * BKT, As + 16384, Bs + 16384, wid);
  #pragma unroll
  for (int t = 0; t < NKT; ++t) {
    __builtin_amdgcn_sched_barrier(0);
    if (t < NKT - 2)       asm volatile("s_waitcnt vmcnt(8)" ::: "memory");
    else if (t == NKT - 2) asm volatile("s_waitcnt vmcnt(4)" ::: "memory");
    else                   asm volatile("s_waitcnt vmcnt(0)" ::: "memory");
    __builtin_amdgcn_s_barrier();
    __builtin_amdgcn_sched_barrier(0);
    if (t + 3 < NKT)
      issue_stage(s, (t + 3) * BKT, As + ((t + 3) & 3) * 8192,
                  Bs + ((t + 3) & 3) * 8192, wid);
    const unsigned short* as = As + (t & 3) * 8192;
    const unsigned short* bs = Bs + (t & 3) * 8192;
    bf16x8 a[8], b[4];
    #pragma unroll
    for (int m = 0; m < 8; ++m)
      a[m] = *reinterpret_cast<const bf16x8*>(as + (rA + m * 16) * BKT + pa8);
    #pragma unroll
    for (int n = 0; n < 4; ++n)
      b[n] = *reinterpret_cast<const bf16x8*>(bs + (rB + n * 16) * BKT + pb8);
    __builtin_amdgcn_s_setprio(1);
    #pragma unroll
    for (int m = 0; m < 8; ++m)
      #pragma unroll
      for (int n = 0; n < 4; ++n)
        acc[m][n] = __builtin_amdgcn_mfma_f32_16x16x32_bf16(a[m], b[n], acc[m][n], 0, 0, 0);
    __builtin_amdgcn_s_setprio(0);
  }
}

// ---- FF GEMM: C = [relu](A@W^T + bias [+ C]); persistent 2-tile l-blocks ---
// Tiles processed sequentially with full drain + one __syncthreads() between
// (prevents a fast wave's next-tile prologue writing LDS slots a slow wave is
// still reading). No cross-tile pipeline state -> no spill risk (R5 lesson).

template <int RELU, int CADD>
__global__ __launch_bounds__(512, 2) void gemm_ff256(
    const unsigned short* __restrict__ Al, const unsigned short* __restrict__ Wl,
    const float* __restrict__ biasl, unsigned short* __restrict__ Cl, int nblkL,
    const unsigned short* __restrict__ Ag, const unsigned short* __restrict__ Wg,
    const float* __restrict__ biasg, unsigned short* __restrict__ Cg) {
  __shared__ unsigned short As[4 * 8192];
  __shared__ unsigned short Bs[4 * 8192];
  const int tid = threadIdx.x;
  const int lane = tid & 63, wid = tid >> 6;
  const int wr = wid >> 2, wc = wid & 3;

  int b = xcd_remap(blockIdx.x, gridDim.x);
  const unsigned short *A, *W;
  const float* bias;
  unsigned short* C;
  long long maxA, maxStore, bcol;
  int r0, rstride, nt;
  if (b < nblkL) {            // l-problem: 196 row-tiles x 2 cols, 2 tiles/block
    A = Al; W = Wl; bias = biasl; C = Cl; maxA = N_PAD - 1; maxStore = N_PAD;
    bcol = (long long)(b & 1) * 256; r0 = b >> 1; rstride = 98; nt = 2;
  } else {                    // g-problem: 4 row-tiles x 2 cols, 1 tile/block
    int gi = b - nblkL;
    A = Ag; W = Wg; bias = biasg; C = Cg; maxA = N_GRAPH - 1; maxStore = N_GRAPH;
    bcol = (long long)(gi & 1) * 256; r0 = gi >> 1; rstride = 0; nt = 1;
  }

  const int srow = tid >> 2;
  const int sslot = (((tid & 3) ^ ((tid >> 3) & 3))) * 8;
  const unsigned short* Bb0 = W + (bcol + srow) * DD + sslot;
  const unsigned short* Bb1 = W + (bcol + 128 + srow) * DD + sslot;

  const int rA = wr * 128 + (lane & 15);
  const int rB = wc * 64 + (lane & 15);
  const int q = lane >> 4;
  const int pa8 = (q ^ ((rA >> 1) & 3)) * 8;
  const int pb8 = (q ^ ((rB >> 1) & 3)) * 8;

  float bv[4];
  #pragma unroll
  for (int n = 0; n < 4; ++n) bv[n] = bias[bcol + wc * 64 + n * 16 + (lane & 15)];

  f32x4 acc[8][4];
  f32x4 zero = {0.f, 0.f, 0.f, 0.f};

  for (int ti = 0; ti < nt; ++ti) {
    if (ti) __syncthreads();   // protect LDS slot reuse across tiles

    #pragma unroll
    for (int m = 0; m < 8; ++m)
      #pragma unroll
      for (int n = 0; n < 4; ++n) acc[m][n] = zero;

    const long long brow = (long long)(r0 + rstride * ti) * 256;
    long long x0 = brow + srow;        if (x0 > maxA) x0 = maxA;
    long long x1 = brow + 128 + srow;  if (x1 > maxA) x1 = maxA;
    StageSrc s;
    s.a0 = A + x0 * DD + sslot; s.a1 = A + x1 * DD + sslot;
    s.b0 = Bb0; s.b1 = Bb1;

    gemm_core256(s, As, Bs, wid, rA, rB, pa8, pb8, acc);

    #pragma unroll
    for (int m = 0; m < 8; ++m) {
      #pragma unroll
      for (int j = 0; j < 4; ++j) {
        const long long rowg = brow + wr * 128 + m * 16 + (lane >> 4) * 4 + j;
        if (rowg < maxStore) {
          #pragma unroll
          for (int n = 0; n < 4; ++n) {
            const long long col = bcol + wc * 64 + n * 16 + (lane & 15);
            float v = acc[m][n][j] + bv[n];
            if constexpr (RELU) v = fmaxf(v, 0.f);
            if constexpr (CADD) v += bf2f(C[rowg * DD + col]);
            C[rowg * DD + col] = f2bf(v);
          }
        }
      }
    }
  }
}

// ---- res GEMM + fused JSD; 256 persistent blocks, 3-4 tiles sequential -----
// accum[0] = sum_diag (LN2 - softplus(-v))
// accum[1] = sum_all  (softplus(-v) + v)   (rows < N_PAD; zero rows -> ln2)
// accum[2] = sum_diag (softplus(-v) + v)

__global__ __launch_bounds__(512, 2) void gemm_jsd256(
    const unsigned short* __restrict__ A, const unsigned short* __restrict__ B,
    const int* __restrict__ batch, double* __restrict__ accum) {
  __shared__ unsigned short As[4 * 8192];
  __shared__ unsigned short Bs[4 * 8192];
  __shared__ float sred[24];
  const int tid = threadIdx.x;
  const int lane = tid & 63, wid = tid >> 6;
  const int wr = wid >> 2, wc = wid & 3;

  const int b = xcd_remap(blockIdx.x, gridDim.x);   // grid == 256 (8 | 256)
  const long long bcol = (long long)(b & 3) * 256;
  const int r0 = b >> 2;               // 0..63; row-tiles r0 + 64*k < 196
  const int nt = (r0 < 4) ? 4 : 3;

  const int srow = tid >> 2;
  const int sslot = (((tid & 3) ^ ((tid >> 3) & 3))) * 8;
  const unsigned short* Bb0 = B + (bcol + srow) * DD + sslot;
  const unsigned short* Bb1 = B + (bcol + 128 + srow) * DD + sslot;

  const int rA = wr * 128 + (lane & 15);
  const int rB = wc * 64 + (lane & 15);
  const int q = lane >> 4;
  const int pa8 = (q ^ ((rA >> 1) & 3)) * 8;
  const int pb8 = (q ^ ((rB >> 1) & 3)) * 8;

  f32x4 acc[8][4];
  f32x4 zero = {0.f, 0.f, 0.f, 0.f};
  const float LN2 = 0.69314718055994530942f;
  float sAll = 0.f, sPos = 0.f, sDiag = 0.f;

  for (int ti = 0; ti < nt; ++ti) {
    if (ti) __syncthreads();   // protect LDS slot reuse across tiles

    #pragma unroll
    for (int m = 0; m < 8; ++m)
      #pragma unroll
      for (int n = 0; n < 4; ++n) acc[m][n] = zero;

    const long long brow = (long long)(r0 + 64 * ti) * 256;
    long long x0 = brow + srow;        if (x0 > N_PAD - 1) x0 = N_PAD - 1;
    long long x1 = brow + 128 + srow;  if (x1 > N_PAD - 1) x1 = N_PAD - 1;
    StageSrc s;
    s.a0 = A + x0 * DD + sslot; s.a1 = A + x1 * DD + sslot;
    s.b0 = Bb0; s.b1 = Bb1;

    gemm_core256(s, As, Bs, wid, rA, rB, pa8, pb8, acc);

    // epilogue: register-only accumulation, batch[] via cache (no LDS/barrier)
    #pragma unroll
    for (int m = 0; m < 8; ++m) {
      #pragma unroll
      for (int j = 0; j < 4; ++j) {
        const long long rowg = brow + wr * 128 + m * 16 + (lane >> 4) * 4 + j;
        if (rowg < N_PAD) {
          const int bg = (rowg < N_NODE) ? batch[rowg] : -1;
          #pragma unroll
          for (int n = 0; n < 4; ++n) {
            const int col = (int)bcol + wc * 64 + n * 16 + (lane & 15);
            float v = acc[m][n][j];
            float t = __expf(-fabsf(v));
            float spn = fmaxf(-v, 0.f) + __logf(1.0f + t);   // softplus(-v)
            sAll += spn + v;
            if (col == bg) {
              sPos += LN2 - spn;
              sDiag += spn + v;
            }
          }
        }
      }
    }
  }

  #pragma unroll
  for (int off = 32; off > 0; off >>= 1) {
    sAll  += __shfl_down(sAll, off);
    sPos  += __shfl_down(sPos, off);
    sDiag += __shfl_down(sDiag, off);
  }
  if (lane == 0) { sred[wid] = sPos; sred[8 + wid] = sAll; sred[16 + wid] = sDiag; }
  __syncthreads();
  if (tid == 0) {
    float p = 0.f, a = 0.f, d = 0.f;
    #pragma unroll
    for (int w = 0; w < 8; ++w) { p += sred[w]; a += sred[8 + w]; d += sred[16 + w]; }
    atomicAdd(accum,     (double)p);
    atomicAdd(accum + 1, (double)a);
    atomicAdd(accum + 2, (double)d);
  }
}

__global__ void finalize_kernel(const double* __restrict__ accum,
                                float* __restrict__ out) {
  if (threadIdx.x == 0 && blockIdx.x == 0) {
    const double LN2 = 0.6931471805599453094172321;
    double posSum = accum[0];
    double negSum = (accum[1] - accum[2])
                  - ((double)N_PAD * N_GRAPH - (double)N_NODE) * LN2;
    double Epos = posSum / (double)N_NODE;
    double Eneg = negSum / ((double)N_NODE * (double)(N_GRAPH - 1));
    out[0] = (float)(Eneg - Epos);
  }
}

// ---- launch -----------------------------------------------------------------

extern "C" void kernel_launch(void* const* d_in, const int* in_sizes, int n_in,
                              void* d_out, int out_size, void* d_ws, size_t ws_size,
                              hipStream_t stream) {
  const float* node  = (const float*)d_in[0];
  const float* graph = (const float*)d_in[1];
  const int*   batch = (const int*)d_in[2];
  const float* lw0 = (const float*)d_in[3];
  const float* lb0 = (const float*)d_in[4];
  const float* lw1 = (const float*)d_in[5];
  const float* lb1 = (const float*)d_in[6];
  const float* lw2 = (const float*)d_in[7];
  const float* lb2 = (const float*)d_in[8];
  const float* lws = (const float*)d_in[9];
  const float* lbs = (const float*)d_in[10];
  const float* gw0 = (const float*)d_in[11];
  const float* gb0 = (const float*)d_in[12];
  const float* gw1 = (const float*)d_in[13];
  const float* gb1 = (const float*)d_in[14];
  const float* gw2 = (const float*)d_in[15];
  const float* gb2 = (const float*)d_in[16];
  const float* gws = (const float*)d_in[17];
  const float* gbs = (const float*)d_in[18];

  // workspace layout (identical to R2-R5)
  char* ws = (char*)d_ws;
  double*         accum = (double*)ws;                          // 24 B
  unsigned short* WB  = (unsigned short*)(ws + 256);            // 8 x 512x512 bf16
  unsigned short* XB  = (unsigned short*)(ws + 4194560LL);      // [N_PAD,512] bf16
  unsigned short* H1  = (unsigned short*)(ws + 55443712LL);
  unsigned short* H2  = (unsigned short*)(ws + 106692864LL);
  unsigned short* GXB = (unsigned short*)(ws + 157942016LL);
  unsigned short* GH1 = (unsigned short*)(ws + 158990592LL);
  unsigned short* GH2 = (unsigned short*)(ws + 160039168LL);
  if (ws_size < 161087744ULL) return;

  hipMemsetAsync(accum, 0, 32, stream);

  WPtrs wp;
  wp.p[0] = lw0; wp.p[1] = lw1; wp.p[2] = lw2; wp.p[3] = lws;
  wp.p[4] = gw0; wp.p[5] = gw1; wp.p[6] = gw2; wp.p[7] = gws;
  cast_w_kernel<<<1024, 256, 0, stream>>>(wp, WB);
  cast_pad_kernel<<<12512, 256, 0, stream>>>(node, XB, N_NODE, N_PAD);
  cast_pad_kernel<<<256, 256, 0, stream>>>(graph, GXB, N_GRAPH, N_GRAPH);

  dim3 blk(512);
  const int nblkL = 98 * 2;            // l: 98 row-pairs x 2 cols, 2 tiles each
  const int nblkG = 4 * 2;             // g: 4 rows x 2 cols, 1 tile each
  dim3 gff(nblkL + nblkG);             // 204 persistent blocks
  dim3 gr(256);                        // jsd: 64 row-groups x 4 cols, 3-4 tiles

  gemm_ff256<1, 0><<<gff, blk, 0, stream>>>(
      XB, WB + 0 * 262144, lb0, H1, nblkL,
      GXB, WB + 4 * 262144, gb0, GH1);
  gemm_ff256<1, 0><<<gff, blk, 0, stream>>>(
      H1, WB + 1 * 262144, lb1, H2, nblkL,
      GH1, WB + 5 * 262144, gb1, GH2);
  gemm_ff256<1, 0><<<gff, blk, 0, stream>>>(
      H2, WB + 2 * 262144, lb2, H1, nblkL,
      GH2, WB + 6 * 262144, gb2, GH1);
  gemm_ff256<0, 1><<<gff, blk, 0, stream>>>(
      XB, WB + 3 * 262144, lbs, H1, nblkL,
      GXB, WB + 7 * 262144, gbs, GH1);

  zeropad_kernel<<<12, 256, 0, stream>>>(H1);
  gemm_jsd256<<<gr, blk, 0, stream>>>(H1, GH1, batch, accum);
  finalize_kernel<<<1, 64, 0, stream>>>(accum, (float*)d_out);
}

// Round 8
// 305.508 us; speedup vs baseline: 1.5288x; 1.3783x over previous
//
#include <hip/hip_runtime.h>
#include <hip/hip_bf16.h>

#define N_NODE  50000
#define N_PAD   50048   // 391 * 128
#define N_GRAPH 1024
#define DD      512
// 128-tile core (ff):
#define BK      64
#define NT      (DD / BK)   // 8 K-steps
// 256-tile core (jsd):
#define BKT     32
#define NKT     16          // 512 / 32

typedef __attribute__((ext_vector_type(8))) short bf16x8;
typedef __attribute__((ext_vector_type(4))) float f32x4;

__device__ __forceinline__ unsigned short f2bf(float f) {
  unsigned int u = __builtin_bit_cast(unsigned int, f);
  return (unsigned short)((u + 0x7FFFu + ((u >> 16) & 1u)) >> 16);  // RTN-even
}

__device__ __forceinline__ void gload16(const void* g, void* l) {
  __builtin_amdgcn_global_load_lds(
      (const __attribute__((address_space(1))) unsigned int*)g,
      (__attribute__((address_space(3))) unsigned int*)l, 16, 0, 0);
}

// T1: bijective XCD-chunk remap (m204 variant)
__device__ __forceinline__ int xcd_remap(int bid, int nwg) {
  int xcd = bid & 7;
  int local = bid >> 3;
  int q = nwg >> 3, r = nwg & 7;
  int base = (xcd < r) ? xcd * (q + 1) : r * (q + 1) + (xcd - r) * q;
  return base + local;
}

// ---- cast kernels -----------------------------------------------------------

__global__ void cast_pad_kernel(const float* __restrict__ src,
                                unsigned short* __restrict__ dst,
                                int srcRows, int dstRows) {
  long long base = ((long long)blockIdx.x * blockDim.x + threadIdx.x) * 8;
  if (base >= (long long)dstRows * DD) return;
  int row = (int)(base >> 9);
  bf16x8 o;
  if (row < srcRows) {
    float4 x0 = reinterpret_cast<const float4*>(src + base)[0];
    float4 x1 = reinterpret_cast<const float4*>(src + base)[1];
    o[0] = (short)f2bf(x0.x); o[1] = (short)f2bf(x0.y);
    o[2] = (short)f2bf(x0.z); o[3] = (short)f2bf(x0.w);
    o[4] = (short)f2bf(x1.x); o[5] = (short)f2bf(x1.y);
    o[6] = (short)f2bf(x1.z); o[7] = (short)f2bf(x1.w);
  } else {
    for (int i = 0; i < 8; ++i) o[i] = 0;
  }
  *reinterpret_cast<bf16x8*>(dst + base) = o;
}

struct WPtrs { const float* p[8]; };

__global__ void cast_w_kernel(WPtrs ps, unsigned short* __restrict__ dst) {
  long long base = ((long long)blockIdx.x * blockDim.x + threadIdx.x) * 8;
  int mat = (int)(base >> 18);
  int off = (int)(base & 262143LL);
  const float* s = ps.p[mat] + off;
  float4 x0 = reinterpret_cast<const float4*>(s)[0];
  float4 x1 = reinterpret_cast<const float4*>(s)[1];
  bf16x8 o;
  o[0] = (short)f2bf(x0.x); o[1] = (short)f2bf(x0.y);
  o[2] = (short)f2bf(x0.z); o[3] = (short)f2bf(x0.w);
  o[4] = (short)f2bf(x1.x); o[5] = (short)f2bf(x1.y);
  o[6] = (short)f2bf(x1.z); o[7] = (short)f2bf(x1.w);
  *reinterpret_cast<bf16x8*>(dst + base) = o;
}

__global__ void zeropad_kernel(unsigned short* __restrict__ H) {
  long long i = (long long)blockIdx.x * blockDim.x + threadIdx.x;
  long long base = (long long)N_NODE * DD + i * 8;
  if (base < (long long)N_PAD * DD) {
    bf16x8 z;
    for (int k = 0; k < 8; ++k) z[k] = 0;
    *reinterpret_cast<bf16x8*>(H + base) = z;
  }
}

// ============================================================================
// ff side: R2's measured-good 128x128 core (depth-1 prefetch, BK=64)
// ============================================================================
// LDS layout: linear [128][64] elements; LDS[r][slot s] holds G[r][s ^ (r&7)]
// (slots are 8-element/16-byte units); swizzle applied on the GLOBAL source.

__device__ __forceinline__ void stage_tile(const unsigned short* __restrict__ G,
                                           long long rowBase, int kcol,
                                           unsigned short* lds, int tid) {
  const int rr   = tid >> 3;                     // row within 32-row round
  const int csrc = (tid & 7) ^ (rr & 7);         // inverse-swizzled source slot
  const unsigned short* src = G + (rowBase + rr) * DD + kcol + csrc * 8;
  unsigned short* dstbase = lds + ((tid >> 6) << 9);   // wid*512 elems (uniform)
  #pragma unroll
  for (int r = 0; r < 4; ++r)
    gload16(src + (long long)r * 32 * DD, dstbase + r * 2048);
}

__device__ __forceinline__ void gemm_core64(
    const unsigned short* __restrict__ A, const unsigned short* __restrict__ B,
    unsigned short* As, unsigned short* Bs,   // each [2][128*64] elements
    long long brow, long long bcol, int wr, int wc, int lane, int tid,
    f32x4 acc[4][4]) {
  const int rA = wr * 64 + (lane & 15);
  const int rB = wc * 64 + (lane & 15);
  const int c16b = lane >> 4;            // 0..3

  stage_tile(A, brow, 0, As, tid);
  stage_tile(B, bcol, 0, Bs, tid);
  __syncthreads();   // compiler emits vmcnt(0) drain here

  for (int kt = 0; kt < NT; ++kt) {
    const int cur = kt & 1;
    if (kt + 1 < NT) {
      stage_tile(A, brow, (kt + 1) * BK, As + (cur ^ 1) * 8192, tid);
      stage_tile(B, bcol, (kt + 1) * BK, Bs + (cur ^ 1) * 8192, tid);
    }
    const unsigned short* as = As + cur * 8192;
    const unsigned short* bs = Bs + cur * 8192;
    #pragma unroll
    for (int kk = 0; kk < 2; ++kk) {
      bf16x8 a[4], b[4];
      #pragma unroll
      for (int m = 0; m < 4; ++m) {
        const int row = rA + m * 16;
        const int c16 = (c16b + kk * 4) ^ (row & 7);
        a[m] = *reinterpret_cast<const bf16x8*>(as + row * 64 + c16 * 8);
      }
      #pragma unroll
      for (int n = 0; n < 4; ++n) {
        const int row = rB + n * 16;
        const int c16 = (c16b + kk * 4) ^ (row & 7);
        b[n] = *reinterpret_cast<const bf16x8*>(bs + row * 64 + c16 * 8);
      }
      #pragma unroll
      for (int m = 0; m < 4; ++m)
        #pragma unroll
        for (int n = 0; n < 4; ++n)
          acc[m][n] = __builtin_amdgcn_mfma_f32_16x16x32_bf16(a[m], b[n], acc[m][n], 0, 0, 0);
    }
    __syncthreads();   // drains prefetch + protects buffer swap
  }
}

// ---- FF GEMM: C = relu(A@W^T + bias)  [DUAL: + A2@W2^T + bias2] ------------
// Combined grid: tiles [0, nwgL) = l-problem (gridX=4), rest = g-problem.

template <int DUAL>
__global__ __launch_bounds__(256, 2) void gemm_ff_kernel(
    const unsigned short* __restrict__ Al, const unsigned short* __restrict__ Wl,
    const float* __restrict__ biasl, unsigned short* __restrict__ Cl,
    const unsigned short* __restrict__ A2l, const unsigned short* __restrict__ W2l,
    const float* __restrict__ bias2l, int nwgL,
    const unsigned short* __restrict__ Ag, const unsigned short* __restrict__ Wg,
    const float* __restrict__ biasg, unsigned short* __restrict__ Cg,
    const unsigned short* __restrict__ A2g, const unsigned short* __restrict__ W2g,
    const float* __restrict__ bias2g) {
  __shared__ unsigned short As[2 * 8192];
  __shared__ unsigned short Bs[2 * 8192];
  const int tid = threadIdx.x;
  const int lane = tid & 63, wid = tid >> 6;
  const int wr = wid >> 1, wc = wid & 1;

  int tile = xcd_remap(blockIdx.x, gridDim.x);
  const unsigned short *A, *W, *A2, *W2;
  const float *bias, *bias2;
  unsigned short* C;
  if (tile < nwgL) {
    A = Al; W = Wl; bias = biasl; C = Cl; A2 = A2l; W2 = W2l; bias2 = bias2l;
  } else {
    tile -= nwgL;
    A = Ag; W = Wg; bias = biasg; C = Cg; A2 = A2g; W2 = W2g; bias2 = bias2g;
  }
  const long long brow = (long long)(tile >> 2) * 128;
  const long long bcol = (long long)(tile & 3) * 128;

  f32x4 zero = {0.f, 0.f, 0.f, 0.f};
  f32x4 acc[4][4];
  #pragma unroll
  for (int m = 0; m < 4; ++m)
    #pragma unroll
    for (int n = 0; n < 4; ++n) acc[m][n] = zero;

  gemm_core64(A, W, As, Bs, brow, bcol, wr, wc, lane, tid, acc);

  float bv[4];
  #pragma unroll
  for (int n = 0; n < 4; ++n) bv[n] = bias[bcol + wc * 64 + n * 16 + (lane & 15)];

  if constexpr (DUAL) {
    float r[4][4][4];
    #pragma unroll
    for (int m = 0; m < 4; ++m)
      #pragma unroll
      for (int n = 0; n < 4; ++n)
        #pragma unroll
        for (int j = 0; j < 4; ++j)
          r[m][n][j] = fmaxf(acc[m][n][j] + bv[n], 0.f);
    #pragma unroll
    for (int m = 0; m < 4; ++m)
      #pragma unroll
      for (int n = 0; n < 4; ++n) acc[m][n] = zero;

    gemm_core64(A2, W2, As, Bs, brow, bcol, wr, wc, lane, tid, acc);

    float b2[4];
    #pragma unroll
    for (int n = 0; n < 4; ++n) b2[n] = bias2[bcol + wc * 64 + n * 16 + (lane & 15)];

    #pragma unroll
    for (int m = 0; m < 4; ++m) {
      const long long row = brow + wr * 64 + m * 16 + (lane >> 4) * 4;
      #pragma unroll
      for (int j = 0; j < 4; ++j)
        #pragma unroll
        for (int n = 0; n < 4; ++n) {
          const long long col = bcol + wc * 64 + n * 16 + (lane & 15);
          float v = r[m][n][j] + acc[m][n][j] + b2[n];
          C[(row + j) * DD + col] = f2bf(v);
        }
    }
  } else {
    #pragma unroll
    for (int m = 0; m < 4; ++m) {
      const long long row = brow + wr * 64 + m * 16 + (lane >> 4) * 4;
      #pragma unroll
      for (int j = 0; j < 4; ++j)
        #pragma unroll
        for (int n = 0; n < 4; ++n) {
          const long long col = bcol + wc * 64 + n * 16 + (lane & 15);
          float v = fmaxf(acc[m][n][j] + bv[n], 0.f);
          C[(row + j) * DD + col] = f2bf(v);
        }
    }
  }
}

// ============================================================================
// jsd side: R4's measured-good 256x256 single-tile core (BK=32, 4-slot,
// counted vmcnt, T2 swizzle). Straight-line body only — no outer tile loop
// (R5/R6 lesson: any persistence wrapper around this core spills).
// ============================================================================

struct StageSrc { const unsigned short *a0, *a1, *b0, *b1; };

__device__ __forceinline__ void issue_stage(const StageSrc& s, int kelem,
                                            unsigned short* sA, unsigned short* sB,
                                            int wid) {
  unsigned short* dA = sA + wid * 512;   // wave-uniform; HW adds lane*16B
  unsigned short* dB = sB + wid * 512;
  gload16(s.a0 + kelem, dA);
  gload16(s.a1 + kelem, dA + 4096);
  gload16(s.b0 + kelem, dB);
  gload16(s.b1 + kelem, dB + 4096);
}

__device__ __forceinline__ void gemm_core256(
    const StageSrc& s, unsigned short* As, unsigned short* Bs,
    int wid, int rA, int rB, int pa8, int pb8, f32x4 acc[8][4]) {
  issue_stage(s, 0, As, Bs, wid);
  issue_stage(s, BKT, As + 8192, Bs + 8192, wid);
  issue_stage(s, 2 * BKT, As + 16384, Bs + 16384, wid);
  #pragma unroll
  for (int t = 0; t < NKT; ++t) {
    __builtin_amdgcn_sched_barrier(0);
    if (t < NKT - 2)       asm volatile("s_waitcnt vmcnt(8)" ::: "memory");
    else if (t == NKT - 2) asm volatile("s_waitcnt vmcnt(4)" ::: "memory");
    else                   asm volatile("s_waitcnt vmcnt(0)" ::: "memory");
    __builtin_amdgcn_s_barrier();
    __builtin_amdgcn_sched_barrier(0);
    if (t + 3 < NKT)
      issue_stage(s, (t + 3) * BKT, As + ((t + 3) & 3) * 8192,
                  Bs + ((t + 3) & 3) * 8192, wid);
    const unsigned short* as = As + (t & 3) * 8192;
    const unsigned short* bs = Bs + (t & 3) * 8192;
    bf16x8 a[8], b[4];
    #pragma unroll
    for (int m = 0; m < 8; ++m)
      a[m] = *reinterpret_cast<const bf16x8*>(as + (rA + m * 16) * BKT + pa8);
    #pragma unroll
    for (int n = 0; n < 4; ++n)
      b[n] = *reinterpret_cast<const bf16x8*>(bs + (rB + n * 16) * BKT + pb8);
    __builtin_amdgcn_s_setprio(1);
    #pragma unroll
    for (int m = 0; m < 8; ++m)
      #pragma unroll
      for (int n = 0; n < 4; ++n)
        acc[m][n] = __builtin_amdgcn_mfma_f32_16x16x32_bf16(a[m], b[n], acc[m][n], 0, 0, 0);
    __builtin_amdgcn_s_setprio(0);
  }
}

// accum[0] = sum_diag (LN2 - softplus(-v))
// accum[1] = sum_all  (softplus(-v) + v)   (rows < N_PAD; zero rows -> ln2)
// accum[2] = sum_diag (softplus(-v) + v)

__global__ __launch_bounds__(512, 2) void gemm_jsd256(
    const unsigned short* __restrict__ A, const unsigned short* __restrict__ B,
    const int* __restrict__ batch, double* __restrict__ accum) {
  __shared__ unsigned short As[4 * 8192];
  __shared__ unsigned short Bs[4 * 8192];
  __shared__ int sbatch[256];
  __shared__ float sred[24];
  const int tid = threadIdx.x;
  const int lane = tid & 63, wid = tid >> 6;
  const int wr = wid >> 2, wc = wid & 3;

  const int tile = xcd_remap(blockIdx.x, gridDim.x);
  const long long brow = (long long)(tile >> 2) * 256;
  const long long bcol = (long long)(tile & 3) * 256;

  if (tid < 256) {
    long long gr = brow + tid;
    sbatch[tid] = (gr < N_NODE) ? batch[gr] : -1;
  }

  const int srow = tid >> 2;
  const int sslot = (((tid & 3) ^ ((tid >> 3) & 3))) * 8;
  long long ra0 = brow + srow;        if (ra0 > N_PAD - 1) ra0 = N_PAD - 1;
  long long ra1 = brow + 128 + srow;  if (ra1 > N_PAD - 1) ra1 = N_PAD - 1;
  StageSrc s;
  s.a0 = A + ra0 * DD + sslot;
  s.a1 = A + ra1 * DD + sslot;
  s.b0 = B + (bcol + srow) * DD + sslot;
  s.b1 = B + (bcol + 128 + srow) * DD + sslot;

  const int rA = wr * 128 + (lane & 15);
  const int rB = wc * 64 + (lane & 15);
  const int q = lane >> 4;
  const int pa8 = (q ^ ((rA >> 1) & 3)) * 8;
  const int pb8 = (q ^ ((rB >> 1) & 3)) * 8;

  f32x4 acc[8][4];
  f32x4 zero = {0.f, 0.f, 0.f, 0.f};
  #pragma unroll
  for (int m = 0; m < 8; ++m)
    #pragma unroll
    for (int n = 0; n < 4; ++n) acc[m][n] = zero;

  gemm_core256(s, As, Bs, wid, rA, rB, pa8, pb8, acc);

  const float LN2 = 0.69314718055994530942f;
  float sAll = 0.f, sPos = 0.f, sDiag = 0.f;
  #pragma unroll
  for (int m = 0; m < 8; ++m) {
    #pragma unroll
    for (int j = 0; j < 4; ++j) {
      const int lr = wr * 128 + m * 16 + (lane >> 4) * 4 + j;
      const long long rowg = brow + lr;
      if (rowg < N_PAD) {
        const int bg = sbatch[lr];
        #pragma unroll
        for (int n = 0; n < 4; ++n) {
          const int col = (int)bcol + wc * 64 + n * 16 + (lane & 15);
          float v = acc[m][n][j];
          float t = __expf(-fabsf(v));
          float spn = fmaxf(-v, 0.f) + __logf(1.0f + t);   // softplus(-v)
          sAll += spn + v;
          if (col == bg) {
            sPos += LN2 - spn;
            sDiag += spn + v;
          }
        }
      }
    }
  }
  #pragma unroll
  for (int off = 32; off > 0; off >>= 1) {
    sAll  += __shfl_down(sAll, off);
    sPos  += __shfl_down(sPos, off);
    sDiag += __shfl_down(sDiag, off);
  }
  if (lane == 0) { sred[wid] = sPos; sred[8 + wid] = sAll; sred[16 + wid] = sDiag; }
  __syncthreads();
  if (tid == 0) {
    float p = 0.f, a = 0.f, d = 0.f;
    #pragma unroll
    for (int w = 0; w < 8; ++w) { p += sred[w]; a += sred[8 + w]; d += sred[16 + w]; }
    atomicAdd(accum,     (double)p);
    atomicAdd(accum + 1, (double)a);
    atomicAdd(accum + 2, (double)d);
  }
}

__global__ void finalize_kernel(const double* __restrict__ accum,
                                float* __restrict__ out) {
  if (threadIdx.x == 0 && blockIdx.x == 0) {
    const double LN2 = 0.6931471805599453094172321;
    double posSum = accum[0];
    double negSum = (accum[1] - accum[2])
                  - ((double)N_PAD * N_GRAPH - (double)N_NODE) * LN2;
    double Epos = posSum / (double)N_NODE;
    double Eneg = negSum / ((double)N_NODE * (double)(N_GRAPH - 1));
    out[0] = (float)(Eneg - Epos);
  }
}

// ---- launch -----------------------------------------------------------------

extern "C" void kernel_launch(void* const* d_in, const int* in_sizes, int n_in,
                              void* d_out, int out_size, void* d_ws, size_t ws_size,
                              hipStream_t stream) {
  const float* node  = (const float*)d_in[0];
  const float* graph = (const float*)d_in[1];
  const int*   batch = (const int*)d_in[2];
  const float* lw0 = (const float*)d_in[3];
  const float* lb0 = (const float*)d_in[4];
  const float* lw1 = (const float*)d_in[5];
  const float* lb1 = (const float*)d_in[6];
  const float* lw2 = (const float*)d_in[7];
  const float* lb2 = (const float*)d_in[8];
  const float* lws = (const float*)d_in[9];
  const float* lbs = (const float*)d_in[10];
  const float* gw0 = (const float*)d_in[11];
  const float* gb0 = (const float*)d_in[12];
  const float* gw1 = (const float*)d_in[13];
  const float* gb1 = (const float*)d_in[14];
  const float* gw2 = (const float*)d_in[15];
  const float* gb2 = (const float*)d_in[16];
  const float* gws = (const float*)d_in[17];
  const float* gbs = (const float*)d_in[18];

  // workspace layout (identical to R2-R6)
  char* ws = (char*)d_ws;
  double*         accum = (double*)ws;                          // 24 B
  unsigned short* WB  = (unsigned short*)(ws + 256);            // 8 x 512x512 bf16
  unsigned short* XB  = (unsigned short*)(ws + 4194560LL);      // [N_PAD,512] bf16
  unsigned short* H1  = (unsigned short*)(ws + 55443712LL);
  unsigned short* H2  = (unsigned short*)(ws + 106692864LL);
  unsigned short* GXB = (unsigned short*)(ws + 157942016LL);
  unsigned short* GH1 = (unsigned short*)(ws + 158990592LL);
  unsigned short* GH2 = (unsigned short*)(ws + 160039168LL);
  if (ws_size < 161087744ULL) return;

  hipMemsetAsync(accum, 0, 32, stream);

  WPtrs wp;
  wp.p[0] = lw0; wp.p[1] = lw1; wp.p[2] = lw2; wp.p[3] = lws;
  wp.p[4] = gw0; wp.p[5] = gw1; wp.p[6] = gw2; wp.p[7] = gws;
  cast_w_kernel<<<1024, 256, 0, stream>>>(wp, WB);
  cast_pad_kernel<<<12512, 256, 0, stream>>>(node, XB, N_NODE, N_PAD);
  cast_pad_kernel<<<256, 256, 0, stream>>>(graph, GXB, N_GRAPH, N_GRAPH);

  // ---- ff chain: R2's 128² kernels, combined l+g grid ----
  dim3 blk256(256);
  const int nwgL = 4 * 391;           // l-problem tiles (gridX=4)
  const int nwgG = 4 * 8;             // g-problem tiles
  dim3 gff(nwgL + nwgG);              // 1596 + 32 blocks, 2 blocks/CU

  gemm_ff_kernel<0><<<gff, blk256, 0, stream>>>(
      XB, WB + 0 * 262144, lb0, H1, nullptr, nullptr, nullptr, nwgL,
      GXB, WB + 4 * 262144, gb0, GH1, nullptr, nullptr, nullptr);
  gemm_ff_kernel<0><<<gff, blk256, 0, stream>>>(
      H1, WB + 1 * 262144, lb1, H2, nullptr, nullptr, nullptr, nwgL,
      GH1, WB + 5 * 262144, gb1, GH2, nullptr, nullptr, nullptr);
  gemm_ff_kernel<1><<<gff, blk256, 0, stream>>>(
      H2, WB + 2 * 262144, lb2, H1, XB, WB + 3 * 262144, lbs, nwgL,
      GH2, WB + 6 * 262144, gb2, GH1, GXB, WB + 7 * 262144, gbs);

  zeropad_kernel<<<12, 256, 0, stream>>>(H1);

  // ---- jsd: R4's 256² single-tile kernel ----
  dim3 blk512(512);
  dim3 gr(196 * 4);                   // 784 blocks
  gemm_jsd256<<<gr, blk512, 0, stream>>>(H1, GH1, batch, accum);
  finalize_kernel<<<1, 64, 0, stream>>>(accum, (float*)d_out);
}